// Round 10
// baseline (58.855 us; speedup 1.0000x reference)
//
#include <hip/hip_runtime.h>
#include <hip/hip_bf16.h>

// Problem constants (fixed by the reference):
// B=16, S=40, P=512, L=48, SEQ=2048, H=1024
#define CB   16
#define CS   40
#define CP   512
#define CL   48
#define CSEQ 2048
#define CH   1024
#define H4   (CH / 4)        // 256 float4 per row
#define NSENT (CB * CS)      // 640 sentences
#define NPAIR (CB * CP)      // 8192 cls pairs

typedef float fvec4 __attribute__((ext_vector_type(4)));

// In-wave bookkeeping:
// tok[s'] = (s' < pl) ? sl[b,s']-1 : 0 ; start = 1 + excl_cumsum(tok)
__device__ __forceinline__ void sentence_meta(
    const int* __restrict__ sentence_length,
    const int* __restrict__ passage_length,
    int b, int s, int lane, int& tok, int& start) {
    const int pl = passage_length[b];
    int tokl = 0;
    if (lane < CS && lane < pl) tokl = sentence_length[b * CS + lane] - 1;
    int x = tokl;
    #pragma unroll
    for (int off = 1; off < 64; off <<= 1) {
        int y = __shfl_up(x, off);
        if (lane >= off) x += y;
    }
    tok   = __shfl(tokl, s);
    start = 1 + __shfl(x, s) - tok;
}

// ---------------------------------------------------------------------------
// Kernel 1 (copy-mode): gather VALID rows only (t < tok) + sent_sum.
// ~62 MB nt-read + ~70 MB write  ->  ~1:1 copy-like mix (target ~6.3 TB/s).
// The zero tails of sen_emb are NOT written here (they don't depend on
// top_rep and would skew this kernel's read:write mix) — K2 writes them.
// ---------------------------------------------------------------------------
__global__ void __launch_bounds__(256)
gather_kernel(const float* __restrict__ top_rep,
              const int* __restrict__ sentence_length,
              const int* __restrict__ passage_length,
              float* __restrict__ sen_emb,
              float* __restrict__ sent_sum) {
    const int bs   = blockIdx.x;             // b*CS + s
    const int b    = bs / CS;
    const int s    = bs - b * CS;
    const int h4   = threadIdx.x;            // float4 column 0..255
    const int lane = threadIdx.x & 63;

    int tok, start;
    sentence_meta(sentence_length, passage_length, b, s, lane, tok, start);

    const fvec4* __restrict__ rep =
        reinterpret_cast<const fvec4*>(top_rep) + (size_t)b * CSEQ * H4;
    fvec4* __restrict__ out =
        reinterpret_cast<fvec4*>(sen_emb) + (size_t)bs * CL * H4;

    fvec4 acc = {0.f, 0.f, 0.f, 0.f};

    // Runtime trip count (block-uniform): only valid rows touched.
    #pragma unroll 8
    for (int t = 0; t < tok; ++t) {
        int row = start + t;                   // valid rows are in-range;
        row = min(max(row, 0), CSEQ - 1);      // clamp for safety
        fvec4 v = __builtin_nontemporal_load(&rep[(size_t)row * H4 + h4]);
        out[(size_t)t * H4 + h4] = v;
        acc += v;
    }

    reinterpret_cast<fvec4*>(sent_sum)[(size_t)bs * H4 + h4] = acc;
}

// ---------------------------------------------------------------------------
// Kernel 2 (write-mode): zero tails + cls, one dispatch, ~89 MB pure writes.
// Blocks 0..639:    sen_emb rows t = tok..47 <- 0   (depends only on lengths)
// Blocks 640..8831: cls pair j = k-640 (sent_sum reads are L2/L3-resident,
//                   published by the K1->K2 kernel boundary)
// ---------------------------------------------------------------------------
__global__ void __launch_bounds__(256)
tail_cls_kernel(const int* __restrict__ sentence_length,
                const int* __restrict__ passage_length,
                const int* __restrict__ pairs_list,
                const int* __restrict__ pairs_num,
                const float* __restrict__ sent_sum,
                float* __restrict__ sen_emb,
                float* __restrict__ cls) {
    const int k    = blockIdx.x;
    const int h4   = threadIdx.x;            // float4 column 0..255
    const int lane = threadIdx.x & 63;

    if (k < NSENT) {
        // ---- zero tail of sentence bs = k ----
        const int b = k / CS;
        const int s = k - b * CS;

        int tok, start;
        sentence_meta(sentence_length, passage_length, b, s, lane, tok, start);

        fvec4* __restrict__ out =
            reinterpret_cast<fvec4*>(sen_emb) + (size_t)k * CL * H4;
        const fvec4 z = {0.f, 0.f, 0.f, 0.f};

        #pragma unroll 8
        for (int t = tok; t < CL; ++t)
            __builtin_nontemporal_store(z, &out[(size_t)t * H4 + h4]);
    } else {
        // ---- cls pair j = k - NSENT ----
        const int j = k - NSENT;
        const int b = j >> 9;                // j / CP
        const int i = j & (CP - 1);

        fvec4 r = {0.f, 0.f, 0.f, 0.f};

        if (i < pairs_num[b]) {
            int p0 = pairs_list[(size_t)j * 2 + 0];
            int p1 = pairs_list[(size_t)j * 2 + 1];
            p0 = min(max(p0, 0), CS - 1);
            p1 = min(max(p1, 0), CS - 1);

            const int pl = passage_length[b];
            const float c0 = (p0 < pl) ? (float)(sentence_length[b * CS + p0] - 1) : 0.f;
            const float c1 = (p1 < pl) ? (float)(sentence_length[b * CS + p1] - 1) : 0.f;
            const float denom = fmaxf(c0 + c1, 1.0f);

            const fvec4* __restrict__ ss = reinterpret_cast<const fvec4*>(sent_sum);
            fvec4 a0 = ss[(size_t)(b * CS + p0) * H4 + h4];
            fvec4 a1 = ss[(size_t)(b * CS + p1) * H4 + h4];
            r = (a0 + a1) / denom;
        }

        __builtin_nontemporal_store(
            r, &reinterpret_cast<fvec4*>(cls)[(size_t)j * H4 + h4]);
    }
}

// ---------------------------------------------------------------------------
// Launch
// ---------------------------------------------------------------------------
extern "C" void kernel_launch(void* const* d_in, const int* in_sizes, int n_in,
                              void* d_out, int out_size, void* d_ws, size_t ws_size,
                              hipStream_t stream) {
    const int*   sentence_length = (const int*)  d_in[0];   // (B,S)
    const int*   pairs_list      = (const int*)  d_in[1];   // (B,P,2)
    const int*   passage_length  = (const int*)  d_in[2];   // (B,)
    const int*   pairs_num       = (const int*)  d_in[3];   // (B,)
    // d_in[4] = max_sentence_length scalar (compile-time CL here)
    const float* top_rep         = (const float*)d_in[5];   // (B,SEQ,H)

    float* out     = (float*)d_out;
    float* sen_emb = out;                                   // (B,S,L,H)
    float* cls     = out + (size_t)CB * CS * CL * CH;       // (B,P,1,H)

    // Workspace: sent_sum (B*S*H f32 = 2.6 MB)
    float* sent_sum = (float*)d_ws;

    gather_kernel<<<NSENT, 256, 0, stream>>>(
        top_rep, sentence_length, passage_length, sen_emb, sent_sum);

    tail_cls_kernel<<<NSENT + NPAIR, 256, 0, stream>>>(
        sentence_length, passage_length, pairs_list, pairs_num,
        sent_sum, sen_emb, cls);
}

// Round 11
// 42.155 us; speedup vs baseline: 1.3962x; 1.3962x over previous
//
#include <hip/hip_runtime.h>
#include <hip/hip_bf16.h>

// Problem constants (fixed by the reference):
// B=16, S=40, P=512, L=48, SEQ=2048, H=1024
#define CB   16
#define CS   40
#define CP   512
#define CL   48
#define CSEQ 2048
#define CH   1024
#define H4   (CH / 4)        // 256 float4 per row
#define NSENT (CB * CS)      // 640 sentences
#define NPAIR (CB * CP)      // 8192 cls pairs

typedef float fvec4 __attribute__((ext_vector_type(4)));

// ---------------------------------------------------------------------------
// BEST KNOWN (42.2 us, reproduced 3x): single-pass gather + in-register
// column sums; separate cls kernel (kernel boundary = the cheap agent-scope
// publish for sent_sum; intra-grid agent atomics cost 5-30x — R4/R6).
// Block shape is a free variable (64/256/1024 thr all equal); 256 kept.
// Store/load cache hints are neutral (R9); phase-splitting regresses (R8/R10).
// ---------------------------------------------------------------------------
__global__ void __launch_bounds__(256)
gather_kernel(const float* __restrict__ top_rep,
              const int* __restrict__ sentence_length,
              const int* __restrict__ passage_length,
              float* __restrict__ sen_emb,
              float* __restrict__ sent_sum) {
    const int bs   = blockIdx.x;             // b*CS + s
    const int b    = bs / CS;
    const int s    = bs - b * CS;
    const int h4   = threadIdx.x;            // float4 column 0..255
    const int lane = threadIdx.x & 63;

    // tok[s'] = (s' < pl) ? sl[b,s']-1 : 0 ; start = 1 + excl_cumsum(tok)
    const int pl = passage_length[b];
    int tokl = 0;
    if (lane < CS && lane < pl) tokl = sentence_length[b * CS + lane] - 1;
    int x = tokl;
    #pragma unroll
    for (int off = 1; off < 64; off <<= 1) {
        int y = __shfl_up(x, off);
        if (lane >= off) x += y;
    }
    const int tok   = __shfl(tokl, s);
    const int start = 1 + __shfl(x, s) - tok;

    const fvec4* __restrict__ rep =
        reinterpret_cast<const fvec4*>(top_rep) + (size_t)b * CSEQ * H4;
    fvec4* __restrict__ out =
        reinterpret_cast<fvec4*>(sen_emb) + (size_t)bs * CL * H4;

    fvec4 acc = {0.f, 0.f, 0.f, 0.f};

    #pragma unroll 8
    for (int t = 0; t < CL; ++t) {
        fvec4 v = {0.f, 0.f, 0.f, 0.f};
        if (t < tok) {
            int row = start + t;               // valid rows are in-range;
            row = min(max(row, 0), CSEQ - 1);  // clamp for safety
            v = rep[(size_t)row * H4 + h4];
        }
        __builtin_nontemporal_store(v, &out[(size_t)t * H4 + h4]);
        acc += v;
    }

    reinterpret_cast<fvec4*>(sent_sum)[(size_t)bs * H4 + h4] = acc;
}

// ---------------------------------------------------------------------------
// Kernel B: cls = masked (sent_sum[p0] + sent_sum[p1]) / max(c0+c1, 1)
// Counts derived directly from sentence_length/passage_length.
// ---------------------------------------------------------------------------
__global__ void __launch_bounds__(256)
cls_kernel(const int* __restrict__ pairs_list,
           const int* __restrict__ pairs_num,
           const int* __restrict__ sentence_length,
           const int* __restrict__ passage_length,
           const float* __restrict__ sent_sum,
           float* __restrict__ cls) {
    const int blk = blockIdx.x;              // b*CP + i
    const int b   = blk >> 9;
    const int i   = blk & (CP - 1);
    const int h4  = threadIdx.x;

    fvec4 r = {0.f, 0.f, 0.f, 0.f};

    if (i < pairs_num[b]) {
        int p0 = pairs_list[(size_t)blk * 2 + 0];
        int p1 = pairs_list[(size_t)blk * 2 + 1];
        p0 = min(max(p0, 0), CS - 1);
        p1 = min(max(p1, 0), CS - 1);

        const int pl = passage_length[b];
        const float c0 = (p0 < pl) ? (float)(sentence_length[b * CS + p0] - 1) : 0.f;
        const float c1 = (p1 < pl) ? (float)(sentence_length[b * CS + p1] - 1) : 0.f;
        const float denom = fmaxf(c0 + c1, 1.0f);

        const fvec4* __restrict__ ss = reinterpret_cast<const fvec4*>(sent_sum);
        fvec4 a0 = ss[(size_t)(b * CS + p0) * H4 + h4];
        fvec4 a1 = ss[(size_t)(b * CS + p1) * H4 + h4];
        r = (a0 + a1) / denom;
    }

    __builtin_nontemporal_store(
        r, &reinterpret_cast<fvec4*>(cls)[(size_t)blk * H4 + h4]);
}

// ---------------------------------------------------------------------------
// Launch
// ---------------------------------------------------------------------------
extern "C" void kernel_launch(void* const* d_in, const int* in_sizes, int n_in,
                              void* d_out, int out_size, void* d_ws, size_t ws_size,
                              hipStream_t stream) {
    const int*   sentence_length = (const int*)  d_in[0];   // (B,S)
    const int*   pairs_list      = (const int*)  d_in[1];   // (B,P,2)
    const int*   passage_length  = (const int*)  d_in[2];   // (B,)
    const int*   pairs_num       = (const int*)  d_in[3];   // (B,)
    // d_in[4] = max_sentence_length scalar (compile-time CL here)
    const float* top_rep         = (const float*)d_in[5];   // (B,SEQ,H)

    float* out     = (float*)d_out;
    float* sen_emb = out;                                   // (B,S,L,H)
    float* cls     = out + (size_t)CB * CS * CL * CH;       // (B,P,1,H)

    // Workspace: sent_sum (B*S*H f32 = 2.6 MB)
    float* sent_sum = (float*)d_ws;

    gather_kernel<<<NSENT, 256, 0, stream>>>(
        top_rep, sentence_length, passage_length, sen_emb, sent_sum);

    cls_kernel<<<NPAIR, 256, 0, stream>>>(
        pairs_list, pairs_num, sentence_length, passage_length, sent_sum, cls);
}